// Round 17
// baseline (1257.777 us; speedup 1.0000x reference)
//
#include <hip/hip_runtime.h>
#include <math.h>

#define L_SEQ 6464
#define DM 64
#define DI 128
#define DS 16
#define CLEN 32          // scan chunk length (6464 = 202 * 32)
#define NCHK 202
#define CTOT (NCHK * 2048)   // carries per dir: 202 chunks * 16 s * 128 d

// ------- fused prologue: concat+pos -> @W_fcc+b_fcc (x0) -> xz = x0 @ W_in ; 8 rows/block -------
__global__ void __launch_bounds__(256) k_front0(
        const float* __restrict__ DNA, const float* __restrict__ CpG,
        const float* __restrict__ cell, const float* __restrict__ pos,
        const float* __restrict__ Wfcc, const float* __restrict__ bfcc,
        const float* __restrict__ Win, float* __restrict__ x0,
        float* __restrict__ xz) {
    __shared__ float s_in[8][64];
    __shared__ float s_x[8][64];
    int t0 = blockIdx.x * 8;
    int tid = threadIdx.x;
    for (int e = tid; e < 8 * 64; e += 256) {
        int r = e >> 6, j = e & 63;
        int l = t0 + r;
        float v;
        if (j < 16)       v = CpG[l * 16 + j];
        else if (j < 32)  v = cell[l * 16 + (j - 16)];
        else              v = DNA[l * 32 + (j - 32)];
        s_in[r][j] = v + pos[l * 64 + j];
    }
    __syncthreads();
    for (int e = tid; e < 8 * 64; e += 256) {
        int r = e >> 6, j = e & 63;
        float acc = bfcc[j];
        for (int i = 0; i < 64; i++) acc += s_in[r][i] * Wfcc[i * 64 + j];
        s_x[r][j] = acc;
        x0[(size_t)(t0 + r) * 64 + j] = acc;   // residual input for layer 0
    }
    __syncthreads();
    int j = tid;  // 256 cols
    float acc[8];
    #pragma unroll
    for (int r = 0; r < 8; r++) acc[r] = 0.f;
    for (int i = 0; i < 64; i++) {
        float w = Win[i * 256 + j];
        #pragma unroll
        for (int r = 0; r < 8; r++) acc[r] = fmaf(s_x[r][i], w, acc[r]);
    }
    #pragma unroll
    for (int r = 0; r < 8; r++) xz[(size_t)(t0 + r) * 256 + j] = acc[r];
}

// ------- fused depthwise conv(+silu) ONE dir (blockIdx.y) + xdbl (vec4) + dt/B/C -------
__global__ void __launch_bounds__(256) k_convdt(
        const float* __restrict__ xz, const float* __restrict__ convw,
        const float* __restrict__ convb, const float* __restrict__ Wxp,
        const float* __restrict__ Wdt, const float* __restrict__ bdt,
        float* __restrict__ xc, float* __restrict__ dt, float* __restrict__ BC) {
    __shared__ __align__(16) float s_xi[22][128];   // rows t0-3 .. t0+18
    __shared__ __align__(16) float s_xc[16][128];
    __shared__ float s_xd[16][36];
    __shared__ __align__(16) float s_wxpT[36][132]; // transposed W_xp, padded
    int t0 = blockIdx.x * 16;
    int dir = blockIdx.y;
    int tid = threadIdx.x;
    for (int i = tid; i < 36 * 128; i += 256) {
        int ii = i / 36, t = i - ii * 36;   // Wxp[ii][t] at linear index i
        s_wxpT[t][ii] = Wxp[i];
    }
    for (int i = tid; i < 22 * 32; i += 256) {
        int rr = i >> 5, q = i & 31;
        int r = t0 - 3 + rr;
        float4 v = make_float4(0.f, 0.f, 0.f, 0.f);
        if (r >= 0 && r < L_SEQ) v = *(const float4*)&xz[(size_t)r * 256 + 4 * q];
        s_xi[rr][4 * q + 0] = v.x;
        s_xi[rr][4 * q + 1] = v.y;
        s_xi[rr][4 * q + 2] = v.z;
        s_xi[rr][4 * q + 3] = v.w;
    }
    __syncthreads();
    // conv + silu
    for (int i = tid; i < 16 * 128; i += 256) {
        int rr = i >> 7, d = i & 127;
        int lr = rr + 3;
        float acc = convb[d];
        if (dir == 0) {
            #pragma unroll
            for (int k = 0; k < 4; k++) acc += convw[d * 4 + k] * s_xi[lr - 3 + k][d];
        } else {
            #pragma unroll
            for (int k = 0; k < 4; k++) acc += convw[d * 4 + k] * s_xi[lr + 3 - k][d];
        }
        float v = acc / (1.f + expf(-acc));
        s_xc[rr][d] = v;
        xc[((size_t)dir * L_SEQ + t0 + rr) * 128 + d] = v;
    }
    __syncthreads();
    // xdbl = xc @ W_xp (36 cols), vec4 over i (same summation order as scalar)
    for (int o = tid; o < 16 * 36; o += 256) {
        int rr = o / 36, t = o % 36;
        float acc = 0.f;
        #pragma unroll 8
        for (int i = 0; i < 128; i += 4) {
            const float4 xv = *(const float4*)&s_xc[rr][i];
            const float4 wv = *(const float4*)&s_wxpT[t][i];
            acc = fmaf(xv.x, wv.x, acc);
            acc = fmaf(xv.y, wv.y, acc);
            acc = fmaf(xv.z, wv.z, acc);
            acc = fmaf(xv.w, wv.w, acc);
        }
        s_xd[rr][t] = acc;
    }
    __syncthreads();
    // dt = softplus(xdbl[:, :4] @ W_dt + b_dt); B,C passthrough
    for (int o = tid; o < 16 * 128; o += 256) {
        int rr = o >> 7, d = o & 127;
        float pre = bdt[d];
        #pragma unroll
        for (int r = 0; r < 4; r++) pre += s_xd[rr][r] * Wdt[r * 128 + d];
        float dtv = (pre > 20.f) ? pre : log1pf(expf(pre));
        dt[((size_t)dir * L_SEQ + t0 + rr) * 128 + d] = dtv;
    }
    for (int o = tid; o < 16 * 32; o += 256) {
        int rr = o >> 5, w = o & 31;
        BC[((size_t)dir * L_SEQ + t0 + rr) * 32 + w] = s_xd[rr][4 + w];
    }
}

// ======= scan, CLEN=32 chunks, pair-state layout: thread = (channel, 2 states) =======
// pass A: per-chunk (a_prod, h_end); plain 256-thr blocks, 32-step chains, 1616 blocks.
// Carry composition across chunks stays the ascending-fmaf affine class (absmax=0
// validated at 101/51/26-step granularities).
__global__ void __launch_bounds__(256) k_scanA(
        const float* __restrict__ dt, const float* __restrict__ xc,
        const float* __restrict__ BC, const float* __restrict__ Alog,
        float* __restrict__ cA, float* __restrict__ cB) {
    __shared__ __align__(16) float s_dt[CLEN * 32];
    __shared__ __align__(16) float s_xc[CLEN * 32];
    __shared__ __align__(16) float s_b [CLEN * 16];
    int g    = blockIdx.x;   // channel group of 32 (4)
    int c    = blockIdx.y;   // chunk (202)
    int dir  = blockIdx.z;   // 2
    int tid  = threadIdx.x;  // 256
    int dl = tid >> 3, sp = tid & 7;
    int d = g * 32 + dl;
    const float* dtp = dt + (size_t)dir * L_SEQ * DI;
    const float* xcp = xc + (size_t)dir * L_SEQ * DI;
    const float* bcp = BC + (size_t)dir * L_SEQ * 32;
    int t0 = c * CLEN;
    int slab0 = dir ? (L_SEQ - CLEN - t0) : t0;
    {
        int ro = tid >> 3, q = tid & 7;   // 32 rows x 8 float4
        int row = slab0 + ro;
        int tl = dir ? (CLEN - 1 - ro) : ro;
        *(float4*)&s_dt[tl * 32 + 4 * q] = *(const float4*)&dtp[(size_t)row * DI + g * 32 + 4 * q];
        *(float4*)&s_xc[tl * 32 + 4 * q] = *(const float4*)&xcp[(size_t)row * DI + g * 32 + 4 * q];
    }
    if (tid < CLEN * 4) {
        int ro = tid >> 2, q = tid & 3;   // 32 rows x 4 float4 (B halves of BC)
        int row = slab0 + ro;
        int tl = dir ? (CLEN - 1 - ro) : ro;
        *(float4*)&s_b[tl * 16 + 4 * q] = *(const float4*)&bcp[(size_t)row * 32 + 4 * q];
    }
    float A0 = -expf(Alog[d * 16 + 2 * sp]);
    float A1 = -expf(Alog[d * 16 + 2 * sp + 1]);
    __syncthreads();
    float h0 = 0.f, h1 = 0.f, ap0 = 1.f, ap1 = 1.f;
    #pragma unroll 4
    for (int tl = 0; tl < CLEN; tl++) {
        float dv = s_dt[tl * 32 + dl];
        float xv = s_xc[tl * 32 + dl];
        float t1 = dv * xv;
        float2 bq = *(const float2*)&s_b[tl * 16 + 2 * sp];
        float a0 = __expf(dv * A0); h0 = fmaf(a0, h0, t1 * bq.x); ap0 *= a0;
        float a1 = __expf(dv * A1); h1 = fmaf(a1, h1, t1 * bq.y); ap1 *= a1;
    }
    size_t o0 = (size_t)dir * CTOT + (size_t)c * 2048 + (size_t)(2 * sp) * 128 + d;
    cA[o0] = ap0; cB[o0] = h0;
    cA[o0 + 128] = ap1; cB[o0 + 128] = h1;
}

// fold carries ascending (same fmaf order) -> F[c] = fold of chunks 0..c-1 (202 chunks)
__global__ void __launch_bounds__(256) k_fold(const float* __restrict__ cA,
                                              const float* __restrict__ cB,
                                              float* __restrict__ F) {
    int idx = blockIdx.x * 256 + threadIdx.x;  // 4096 = 2 dirs * 16 s * 128 d
    int dir = idx >> 11;
    int rem = idx & 2047;
    int s = rem >> 7;
    int d = rem & 127;
    size_t o = (size_t)dir * CTOT + (size_t)s * 128 + d;
    float carry = 0.f;
    int cc = 0;
    while (cc < NCHK) {
        int n = (NCHK - cc < 8) ? (NCHK - cc) : 8;
        float av[8], bv[8];
        for (int j = 0; j < n; j++) {
            size_t oo = o + (size_t)(cc + j) * 2048;
            av[j] = cA[oo];
            bv[j] = cB[oo];
        }
        for (int j = 0; j < n; j++) {
            F[o + (size_t)(cc + j) * 2048] = carry;
            carry = fmaf(av[j], carry, bv[j]);
        }
        cc += n;
    }
}

// pass B: replay 32-step chunk from folded carry; Sum_s h*C via balanced tree
// (in-thread pair + xor-1/2/4 butterflies, same order as the original DPP ror16 tree).
__global__ void __launch_bounds__(256) k_scanB(
        const float* __restrict__ dt, const float* __restrict__ xc,
        const float* __restrict__ BC, const float* __restrict__ Alog,
        const float* __restrict__ Dres, const float* __restrict__ F,
        float* __restrict__ y) {
    __shared__ __align__(16) float s_dt[CLEN * 32];   // becomes y in-place
    __shared__ __align__(16) float s_xc[CLEN * 32];
    __shared__ __align__(16) float s_bc[CLEN * 32];
    int g    = blockIdx.x;
    int c    = blockIdx.y;
    int dir  = blockIdx.z;
    int tid  = threadIdx.x;  // 256
    int dl = tid >> 3, sp = tid & 7;
    int d = g * 32 + dl;
    const float* dtp = dt + (size_t)dir * L_SEQ * DI;
    const float* xcp = xc + (size_t)dir * L_SEQ * DI;
    const float* bcp = BC + (size_t)dir * L_SEQ * 32;
    float* yp = y + (size_t)dir * L_SEQ * DI;
    int t0 = c * CLEN;
    int slab0 = dir ? (L_SEQ - CLEN - t0) : t0;
    {
        int ro = tid >> 3, q = tid & 7;
        int row = slab0 + ro;
        int tl = dir ? (CLEN - 1 - ro) : ro;
        *(float4*)&s_dt[tl * 32 + 4 * q] = *(const float4*)&dtp[(size_t)row * DI + g * 32 + 4 * q];
        *(float4*)&s_xc[tl * 32 + 4 * q] = *(const float4*)&xcp[(size_t)row * DI + g * 32 + 4 * q];
        *(float4*)&s_bc[tl * 32 + 4 * q] = *(const float4*)&bcp[(size_t)row * 32 + 4 * q];
    }
    float A0 = -expf(Alog[d * 16 + 2 * sp]);
    float A1 = -expf(Alog[d * 16 + 2 * sp + 1]);
    size_t o0 = (size_t)dir * CTOT + (size_t)c * 2048 + (size_t)(2 * sp) * 128 + d;
    float h0 = F[o0];
    float h1 = F[o0 + 128];
    float Dv = Dres[d];
    __syncthreads();
    #pragma unroll 4
    for (int tl = 0; tl < CLEN; tl++) {
        float dv = s_dt[tl * 32 + dl];
        float xv = s_xc[tl * 32 + dl];
        float t1 = dv * xv;
        float2 bq = *(const float2*)&s_bc[tl * 32 + 2 * sp];
        float2 cq = *(const float2*)&s_bc[tl * 32 + 16 + 2 * sp];
        float a0 = __expf(dv * A0); h0 = fmaf(a0, h0, t1 * bq.x);
        float a1 = __expf(dv * A1); h1 = fmaf(a1, h1, t1 * bq.y);
        float p0 = h0 * cq.x, p1 = h1 * cq.y;
        float qv = p0 + p1;                       // q-level (states 2sp,2sp+1)
        float rv = qv + __shfl_xor(qv, 1);        // r-level
        float uv = rv + __shfl_xor(rv, 2);        // u-level
        float val = uv + __shfl_xor(uv, 4);       // full sum over 16 states
        if (sp == 0) s_dt[tl * 32 + dl] = val + xv * Dv;  // in-place y (same-wave read-before-write)
    }
    __syncthreads();
    {
        int ro = tid >> 3, q = tid & 7;
        int row = slab0 + ro;
        int tl = dir ? (CLEN - 1 - ro) : ro;
        float4 v = *(const float4*)&s_dt[tl * 32 + 4 * q];
        *(float4*)&yp[(size_t)row * DI + g * 32 + 4 * q] = v;
    }
}

// ------- out-GEMM + gate + residual + layernorm + permute + NEXT-LAYER xz; 4 rows/block -------
__global__ void __launch_bounds__(256) k_outln(
        const float* __restrict__ x, const float* __restrict__ y,
        const float* __restrict__ xz, const float* __restrict__ Wout,
        const float* __restrict__ Win, const float* __restrict__ lng,
        const float* __restrict__ lnb, float* __restrict__ xnext,
        float* __restrict__ xznext, int permMode, int doXz) {
    __shared__ float s_g[4][128];
    __shared__ float s_out[4][64];
    __shared__ int s_l2[4];
    int tid = threadIdx.x;
    int w = tid >> 6;        // wave id (row within block)
    int j = tid & 63;
    int l = blockIdx.x * 4 + w;
    float z1 = xz[(size_t)l * 256 + 128 + j];
    float z2 = xz[(size_t)l * 256 + 192 + j];
    float sz1 = z1 / (1.f + expf(-z1));
    float sz2 = z2 / (1.f + expf(-z2));
    s_g[w][j]      = 0.5f * (y[(size_t)l * 128 + j] + y[(size_t)(L_SEQ + l) * 128 + j]) * sz1;
    s_g[w][j + 64] = 0.5f * (y[(size_t)l * 128 + 64 + j] + y[(size_t)(L_SEQ + l) * 128 + 64 + j]) * sz2;
    __syncthreads();
    float acc = x[(size_t)l * 64 + j];
    for (int i = 0; i < 128; i++) acc += s_g[w][i] * Wout[i * 64 + j];
    float m = acc;
    for (int o = 32; o >= 1; o >>= 1) m += __shfl_xor(m, o);
    m *= (1.f / 64.f);
    float dv = acc - m;
    float v = dv * dv;
    for (int o = 32; o >= 1; o >>= 1) v += __shfl_xor(v, o);
    v *= (1.f / 64.f);
    float out = dv * rsqrtf(v + 1e-5f) * lng[j] + lnb[j];
    int l2;
    if (permMode == 0) l2 = (l % 64) * 101 + (l / 64);   // (s,c)->(c,s)
    else               l2 = (l % 101) * 64 + (l / 101);  // (c,s)->(s,c)
    xnext[(size_t)l2 * 64 + j] = out;
    if (!doXz) return;
    // ---- next-layer xz for these 4 (permuted) rows: xz[l2] = out @ W_in
    s_out[w][j] = out;
    if (j == 0) s_l2[w] = l2;
    __syncthreads();
    float xa[4];
    #pragma unroll
    for (int r = 0; r < 4; r++) xa[r] = 0.f;
    for (int i = 0; i < 64; i++) {
        float wv = Win[i * 256 + tid];
        #pragma unroll
        for (int r = 0; r < 4; r++) xa[r] = fmaf(s_out[r][i], wv, xa[r]);
    }
    #pragma unroll
    for (int r = 0; r < 4; r++) xznext[(size_t)s_l2[r] * 256 + tid] = xa[r];
}

// ---------------- epilogue ----------------
__global__ void k_epilogue(const float* __restrict__ x, const float* __restrict__ Wfc,
                           const float* __restrict__ bfc, const float* __restrict__ ytrue,
                           const int* __restrict__ halfwin, const int* __restrict__ rows,
                           float* __restrict__ out) {
    int k = threadIdx.x;  // 64
    int hw = halfwin[0];
    int c = rows[k];
    const float* xr = x + ((size_t)hw * 64 + c) * 64;
    float acc = bfc[0];
    for (int i = 0; i < 64; i++) acc += xr[i] * Wfc[i];
    float s = 1.f / (1.f + expf(-acc));
    float r = 1.f - fabsf(ytrue[k] - s);
    out[k] = r;
}

extern "C" void kernel_launch(void* const* d_in, const int* in_sizes, int n_in,
                              void* d_out, int out_size, void* d_ws, size_t ws_size,
                              hipStream_t stream) {
    const float* DNA   = (const float*)d_in[0];
    const float* CpG   = (const float*)d_in[1];
    const float* cel   = (const float*)d_in[2];
    const float* pos   = (const float*)d_in[3];
    const float* ytrue = (const float*)d_in[4];
    const float* Wfcc  = (const float*)d_in[5];
    const float* bfcc  = (const float*)d_in[6];
    const float* Win   = (const float*)d_in[7];
    const float* convw = (const float*)d_in[8];
    const float* convb = (const float*)d_in[9];
    const float* Wxp   = (const float*)d_in[10];
    const float* Wdt   = (const float*)d_in[11];
    const float* bdt   = (const float*)d_in[12];
    const float* Alog  = (const float*)d_in[13];
    const float* Dres  = (const float*)d_in[14];
    const float* Wout  = (const float*)d_in[15];
    const float* lng   = (const float*)d_in[16];
    const float* lnb   = (const float*)d_in[17];
    const float* Wfc   = (const float*)d_in[18];
    const float* bfc   = (const float*)d_in[19];
    const int* halfwin = (const int*)d_in[20];
    const int* rows    = (const int*)d_in[21];

    float* ws = (float*)d_ws;
    size_t off = 0;
    float* x0  = ws + off; off += (size_t)L_SEQ * 64;
    float* x1  = ws + off; off += (size_t)L_SEQ * 64;
    float* xzA = ws + off; off += (size_t)L_SEQ * 256;
    float* xzB = ws + off; off += (size_t)L_SEQ * 256;
    float* xcb = ws + off; off += (size_t)2 * L_SEQ * 128;
    float* dtb = ws + off; off += (size_t)2 * L_SEQ * 128;
    float* BCb = ws + off; off += (size_t)2 * L_SEQ * 32;
    float* yb  = ws + off; off += (size_t)2 * L_SEQ * 128;
    float* cAb = ws + off; off += (size_t)2 * CTOT;
    float* cBb = ws + off; off += (size_t)2 * CTOT;
    float* Fb  = ws + off; off += (size_t)2 * CTOT;

    float* xcur = x0;
    float* xnxt = x1;
    float* xzc  = xzA;
    float* xzn  = xzB;
    k_front0<<<L_SEQ / 8, 256, 0, stream>>>(DNA, CpG, cel, pos, Wfcc, bfcc, Win, x0, xzc);
    for (int sb = 0; sb < 8; sb++) {
        k_convdt<<<dim3(L_SEQ / 16, 2), 256, 0, stream>>>(xzc, convw, convb, Wxp, Wdt, bdt,
                                                          xcb, dtb, BCb);
        k_scanA<<<dim3(4, NCHK, 2), 256, 0, stream>>>(dtb, xcb, BCb, Alog, cAb, cBb);
        k_fold<<<16, 256, 0, stream>>>(cAb, cBb, Fb);
        k_scanB<<<dim3(4, NCHK, 2), 256, 0, stream>>>(dtb, xcb, BCb, Alog, Dres, Fb, yb);
        k_outln<<<L_SEQ / 4, 256, 0, stream>>>(xcur, yb, xzc, Wout, Win, lng, lnb, xnxt, xzn,
                                               (sb % 2 == 0) ? 0 : 1, (sb < 7) ? 1 : 0);
        float* tmp = xcur; xcur = xnxt; xnxt = tmp;
        float* tz = xzc; xzc = xzn; xzn = tz;
    }

    k_epilogue<<<1, 64, 0, stream>>>(xcur, Wfc, bfc, ytrue, halfwin, rows, (float*)d_out);
}

// Round 18
// 644.590 us; speedup vs baseline: 1.9513x; 1.9513x over previous
//
#include <hip/hip_runtime.h>
#include <math.h>

#define L_SEQ 6464
#define DM 64
#define DI 128
#define DS 16
#define CHUNK 101
#define NCH 64
#define CSZ 262144   // carries per (dir,s,d) table: 2*64*2048

// ------- fused prologue: concat+pos -> @W_fcc+b_fcc (x0) -> xz = x0 @ W_in ; 8 rows/block -------
__global__ void __launch_bounds__(256) k_front0(
        const float* __restrict__ DNA, const float* __restrict__ CpG,
        const float* __restrict__ cell, const float* __restrict__ pos,
        const float* __restrict__ Wfcc, const float* __restrict__ bfcc,
        const float* __restrict__ Win, float* __restrict__ x0,
        float* __restrict__ xz) {
    __shared__ float s_in[8][64];
    __shared__ float s_x[8][64];
    int t0 = blockIdx.x * 8;
    int tid = threadIdx.x;
    for (int e = tid; e < 8 * 64; e += 256) {
        int r = e >> 6, j = e & 63;
        int l = t0 + r;
        float v;
        if (j < 16)       v = CpG[l * 16 + j];
        else if (j < 32)  v = cell[l * 16 + (j - 16)];
        else              v = DNA[l * 32 + (j - 32)];
        s_in[r][j] = v + pos[l * 64 + j];
    }
    __syncthreads();
    for (int e = tid; e < 8 * 64; e += 256) {
        int r = e >> 6, j = e & 63;
        float acc = bfcc[j];
        for (int i = 0; i < 64; i++) acc += s_in[r][i] * Wfcc[i * 64 + j];
        s_x[r][j] = acc;
        x0[(size_t)(t0 + r) * 64 + j] = acc;   // residual input for layer 0
    }
    __syncthreads();
    int j = tid;  // 256 cols
    float acc[8];
    #pragma unroll
    for (int r = 0; r < 8; r++) acc[r] = 0.f;
    for (int i = 0; i < 64; i++) {
        float w = Win[i * 256 + j];
        #pragma unroll
        for (int r = 0; r < 8; r++) acc[r] = fmaf(s_x[r][i], w, acc[r]);
    }
    #pragma unroll
    for (int r = 0; r < 8; r++) xz[(size_t)(t0 + r) * 256 + j] = acc[r];
}

// ------- fused depthwise conv(+silu) ONE dir (blockIdx.y) + xdbl (vec4) + dt/B/C -------
__global__ void __launch_bounds__(256) k_convdt(
        const float* __restrict__ xz, const float* __restrict__ convw,
        const float* __restrict__ convb, const float* __restrict__ Wxp,
        const float* __restrict__ Wdt, const float* __restrict__ bdt,
        float* __restrict__ xc, float* __restrict__ dt, float* __restrict__ BC) {
    __shared__ __align__(16) float s_xi[22][128];   // rows t0-3 .. t0+18
    __shared__ __align__(16) float s_xc[16][128];
    __shared__ float s_xd[16][36];
    __shared__ __align__(16) float s_wxpT[36][132]; // transposed W_xp, padded
    int t0 = blockIdx.x * 16;
    int dir = blockIdx.y;
    int tid = threadIdx.x;
    for (int i = tid; i < 36 * 128; i += 256) {
        int ii = i / 36, t = i - ii * 36;   // Wxp[ii][t] at linear index i
        s_wxpT[t][ii] = Wxp[i];
    }
    for (int i = tid; i < 22 * 32; i += 256) {
        int rr = i >> 5, q = i & 31;
        int r = t0 - 3 + rr;
        float4 v = make_float4(0.f, 0.f, 0.f, 0.f);
        if (r >= 0 && r < L_SEQ) v = *(const float4*)&xz[(size_t)r * 256 + 4 * q];
        s_xi[rr][4 * q + 0] = v.x;
        s_xi[rr][4 * q + 1] = v.y;
        s_xi[rr][4 * q + 2] = v.z;
        s_xi[rr][4 * q + 3] = v.w;
    }
    __syncthreads();
    // conv + silu
    for (int i = tid; i < 16 * 128; i += 256) {
        int rr = i >> 7, d = i & 127;
        int lr = rr + 3;
        float acc = convb[d];
        if (dir == 0) {
            #pragma unroll
            for (int k = 0; k < 4; k++) acc += convw[d * 4 + k] * s_xi[lr - 3 + k][d];
        } else {
            #pragma unroll
            for (int k = 0; k < 4; k++) acc += convw[d * 4 + k] * s_xi[lr + 3 - k][d];
        }
        float v = acc / (1.f + expf(-acc));
        s_xc[rr][d] = v;
        xc[((size_t)dir * L_SEQ + t0 + rr) * 128 + d] = v;
    }
    __syncthreads();
    // xdbl = xc @ W_xp (36 cols), vec4 over i (same summation order as scalar)
    for (int o = tid; o < 16 * 36; o += 256) {
        int rr = o / 36, t = o % 36;
        float acc = 0.f;
        #pragma unroll 8
        for (int i = 0; i < 128; i += 4) {
            const float4 xv = *(const float4*)&s_xc[rr][i];
            const float4 wv = *(const float4*)&s_wxpT[t][i];
            acc = fmaf(xv.x, wv.x, acc);
            acc = fmaf(xv.y, wv.y, acc);
            acc = fmaf(xv.z, wv.z, acc);
            acc = fmaf(xv.w, wv.w, acc);
        }
        s_xd[rr][t] = acc;
    }
    __syncthreads();
    // dt = softplus(xdbl[:, :4] @ W_dt + b_dt); B,C passthrough
    for (int o = tid; o < 16 * 128; o += 256) {
        int rr = o >> 7, d = o & 127;
        float pre = bdt[d];
        #pragma unroll
        for (int r = 0; r < 4; r++) pre += s_xd[rr][r] * Wdt[r * 128 + d];
        float dtv = (pre > 20.f) ? pre : log1pf(expf(pre));
        dt[((size_t)dir * L_SEQ + t0 + rr) * 128 + d] = dtv;
    }
    for (int o = tid; o < 16 * 32; o += 256) {
        int rr = o >> 5, w = o & 31;
        BC[((size_t)dir * L_SEQ + t0 + rr) * 32 + w] = s_xd[rr][4 + w];
    }
}

// ======= scan, pair-state layout: thread = (channel, 2 states); 8 lanes/channel =======
// pass A, 512 thr / 2 segments: seg0 = steps 0..50 (result IS the bit-exact mid capture);
// seg1 = steps 51..100 from identity; chunk carry composed in LDS (affine fmaf class,
// absmax=0 validated at chunk/half/quarter granularity).
__global__ void __launch_bounds__(512) k_scanA(
        const float* __restrict__ dt, const float* __restrict__ xc,
        const float* __restrict__ BC, const float* __restrict__ Alog,
        float* __restrict__ cA, float* __restrict__ cB,
        float* __restrict__ cAm, float* __restrict__ cBm) {
    __shared__ __align__(16) float s_dt[CHUNK * 32];
    __shared__ __align__(16) float s_xc[CHUNK * 32];
    __shared__ __align__(16) float s_b [CHUNK * 16];
    __shared__ float s_lo[256][4];
    int g    = blockIdx.x;   // channel group of 32 (4)
    int c    = blockIdx.y;   // chunk (64)
    int dir  = blockIdx.z;   // 2
    int tid  = threadIdx.x;  // 512
    int seg  = tid >> 8;     // 0: steps 0..50, 1: steps 51..100
    int t8 = tid & 255;
    int dl = t8 >> 3, sp = t8 & 7;
    int d = g * 32 + dl;
    const float* dtp = dt + (size_t)dir * L_SEQ * DI;
    const float* xcp = xc + (size_t)dir * L_SEQ * DI;
    const float* bcp = BC + (size_t)dir * L_SEQ * 32;
    int t0 = c * CHUNK;
    int slab0 = dir ? (L_SEQ - CHUNK - t0) : t0;
    for (int i = tid; i < CHUNK * 8; i += 512) {
        int ro = i >> 3, q = i & 7;
        int row = slab0 + ro;
        int tl = dir ? (CHUNK - 1 - ro) : ro;
        *(float4*)&s_dt[tl * 32 + 4 * q] = *(const float4*)&dtp[(size_t)row * DI + g * 32 + 4 * q];
        *(float4*)&s_xc[tl * 32 + 4 * q] = *(const float4*)&xcp[(size_t)row * DI + g * 32 + 4 * q];
    }
    for (int i = tid; i < CHUNK * 4; i += 512) {
        int ro = i >> 2, q = i & 3;
        int row = slab0 + ro;
        int tl = dir ? (CHUNK - 1 - ro) : ro;
        *(float4*)&s_b[tl * 16 + 4 * q] = *(const float4*)&bcp[(size_t)row * 32 + 4 * q];
    }
    float A0 = -expf(Alog[d * 16 + 2 * sp]);
    float A1 = -expf(Alog[d * 16 + 2 * sp + 1]);
    __syncthreads();
    float h0 = 0.f, h1 = 0.f, ap0 = 1.f, ap1 = 1.f;
    size_t o0 = (size_t)dir * 131072 + (size_t)c * 2048 + (size_t)(2 * sp) * 128 + d;
    int tl0s = seg ? 51 : 0;
    int tl1s = seg ? CHUNK : 51;
    #pragma unroll 4
    for (int tl = tl0s; tl < tl1s; tl++) {
        float dv = s_dt[tl * 32 + dl];
        float xv = s_xc[tl * 32 + dl];
        float t1 = dv * xv;
        float2 bq = *(const float2*)&s_b[tl * 16 + 2 * sp];
        float a0 = __expf(dv * A0); h0 = fmaf(a0, h0, t1 * bq.x); ap0 *= a0;
        float a1 = __expf(dv * A1); h1 = fmaf(a1, h1, t1 * bq.y); ap1 *= a1;
    }
    if (!seg) {
        cAm[o0] = ap0; cBm[o0] = h0;
        cAm[o0 + 128] = ap1; cBm[o0 + 128] = h1;
        s_lo[t8][0] = ap0; s_lo[t8][1] = h0;
        s_lo[t8][2] = ap1; s_lo[t8][3] = h1;
    }
    __syncthreads();
    if (seg) {
        float al0 = s_lo[t8][0], hl0 = s_lo[t8][1];
        float al1 = s_lo[t8][2], hl1 = s_lo[t8][3];
        cA[o0] = al0 * ap0;
        cB[o0] = fmaf(ap0, hl0, h0);
        cA[o0 + 128] = al1 * ap1;
        cB[o0 + 128] = fmaf(ap1, hl1, h1);
    }
}

// fold carries ascending (same fmaf order as the original lookback) -> F[c] = fold of 0..c-1
__global__ void __launch_bounds__(256) k_fold(const float* __restrict__ cA,
                                              const float* __restrict__ cB,
                                              float* __restrict__ F) {
    int idx = blockIdx.x * 256 + threadIdx.x;  // 4096 = 2 dirs * 16 s * 128 d
    int dir = idx >> 11;
    int rem = idx & 2047;
    int s = rem >> 7;
    int d = rem & 127;
    size_t o = (size_t)dir * 131072 + (size_t)s * 128 + d;
    float carry = 0.f;
    for (int cc = 0; cc < NCH; cc += 8) {
        float av[8], bv[8];
        #pragma unroll
        for (int j = 0; j < 8; j++) {
            size_t oo = o + (size_t)(cc + j) * 2048;
            av[j] = cA[oo];
            bv[j] = cB[oo];
        }
        #pragma unroll
        for (int j = 0; j < 8; j++) {
            F[o + (size_t)(cc + j) * 2048] = carry;
            carry = fmaf(av[j], carry, bv[j]);
        }
    }
}

// pass B: 512 thr; lo-half replays steps 0..50 from chunk carry, hi-half replays 51..100
// from the affine-composed mid carry h = fmaf(ap_mid, chi, h_mid).  Sum_s h*C via balanced
// tree (in-thread pair + xor-1/2/4 butterflies, same order as the original DPP ror16 tree).
__global__ void __launch_bounds__(512) k_scanB(
        const float* __restrict__ dt, const float* __restrict__ xc,
        const float* __restrict__ BC, const float* __restrict__ Alog,
        const float* __restrict__ Dres, const float* __restrict__ F,
        const float* __restrict__ cAm, const float* __restrict__ cBm,
        float* __restrict__ y) {
    __shared__ __align__(16) float s_dt[CHUNK * 32];   // becomes y in-place
    __shared__ __align__(16) float s_xc[CHUNK * 32];
    __shared__ __align__(16) float s_bc[CHUNK * 32];
    int g    = blockIdx.x;
    int c    = blockIdx.y;
    int dir  = blockIdx.z;
    int tid  = threadIdx.x;    // 512
    int half = tid >> 8;       // 0: steps 0..50, 1: steps 51..100
    int t8 = tid & 255;
    int dl = t8 >> 3, sp = t8 & 7;
    int d = g * 32 + dl;
    const float* dtp = dt + (size_t)dir * L_SEQ * DI;
    const float* xcp = xc + (size_t)dir * L_SEQ * DI;
    const float* bcp = BC + (size_t)dir * L_SEQ * 32;
    float* yp = y + (size_t)dir * L_SEQ * DI;
    int t0 = c * CHUNK;
    int slab0 = dir ? (L_SEQ - CHUNK - t0) : t0;
    for (int i = tid; i < CHUNK * 8; i += 512) {
        int ro = i >> 3, q = i & 7;
        int row = slab0 + ro;
        int tl = dir ? (CHUNK - 1 - ro) : ro;
        *(float4*)&s_dt[tl * 32 + 4 * q] = *(const float4*)&dtp[(size_t)row * DI + g * 32 + 4 * q];
        *(float4*)&s_xc[tl * 32 + 4 * q] = *(const float4*)&xcp[(size_t)row * DI + g * 32 + 4 * q];
        *(float4*)&s_bc[tl * 32 + 4 * q] = *(const float4*)&bcp[(size_t)row * 32 + 4 * q];
    }
    float A0 = -expf(Alog[d * 16 + 2 * sp]);
    float A1 = -expf(Alog[d * 16 + 2 * sp + 1]);
    size_t o0 = (size_t)dir * 131072 + (size_t)c * 2048 + (size_t)(2 * sp) * 128 + d;
    float h0 = F[o0];
    float h1 = F[o0 + 128];
    if (half) {
        float am0 = cAm[o0], bm0 = cBm[o0];
        float am1 = cAm[o0 + 128], bm1 = cBm[o0 + 128];
        h0 = fmaf(am0, h0, bm0);
        h1 = fmaf(am1, h1, bm1);
    }
    float Dv = Dres[d];
    __syncthreads();
    int tl0 = half ? 51 : 0;
    int tl1 = half ? CHUNK : 51;
    #pragma unroll 4
    for (int tl = tl0; tl < tl1; tl++) {
        float dv = s_dt[tl * 32 + dl];
        float xv = s_xc[tl * 32 + dl];
        float t1 = dv * xv;
        float2 bq = *(const float2*)&s_bc[tl * 32 + 2 * sp];
        float2 cq = *(const float2*)&s_bc[tl * 32 + 16 + 2 * sp];
        float a0 = __expf(dv * A0); h0 = fmaf(a0, h0, t1 * bq.x);
        float a1 = __expf(dv * A1); h1 = fmaf(a1, h1, t1 * bq.y);
        float p0 = h0 * cq.x, p1 = h1 * cq.y;
        float qv = p0 + p1;                       // q-level (states 2sp,2sp+1)
        float rv = qv + __shfl_xor(qv, 1);        // r-level
        float uv = rv + __shfl_xor(rv, 2);        // u-level
        float val = uv + __shfl_xor(uv, 4);       // full sum over 16 states
        if (sp == 0) s_dt[tl * 32 + dl] = val + xv * Dv;  // in-place y (same-wave read-before-write)
    }
    __syncthreads();
    for (int i = tid; i < CHUNK * 8; i += 512) {
        int ro = i >> 3, q = i & 7;
        int row = slab0 + ro;
        int tl = dir ? (CHUNK - 1 - ro) : ro;
        float4 v = *(const float4*)&s_dt[tl * 32 + 4 * q];
        *(float4*)&yp[(size_t)row * DI + g * 32 + 4 * q] = v;
    }
}

// ------- out-GEMM + gate + residual + layernorm + permute + NEXT-LAYER xz; 4 rows/block -------
__global__ void __launch_bounds__(256) k_outln(
        const float* __restrict__ x, const float* __restrict__ y,
        const float* __restrict__ xz, const float* __restrict__ Wout,
        const float* __restrict__ Win, const float* __restrict__ lng,
        const float* __restrict__ lnb, float* __restrict__ xnext,
        float* __restrict__ xznext, int permMode, int doXz) {
    __shared__ float s_g[4][128];
    __shared__ float s_out[4][64];
    __shared__ int s_l2[4];
    int tid = threadIdx.x;
    int w = tid >> 6;        // wave id (row within block)
    int j = tid & 63;
    int l = blockIdx.x * 4 + w;
    float z1 = xz[(size_t)l * 256 + 128 + j];
    float z2 = xz[(size_t)l * 256 + 192 + j];
    float sz1 = z1 / (1.f + expf(-z1));
    float sz2 = z2 / (1.f + expf(-z2));
    s_g[w][j]      = 0.5f * (y[(size_t)l * 128 + j] + y[(size_t)(L_SEQ + l) * 128 + j]) * sz1;
    s_g[w][j + 64] = 0.5f * (y[(size_t)l * 128 + 64 + j] + y[(size_t)(L_SEQ + l) * 128 + 64 + j]) * sz2;
    __syncthreads();
    float acc = x[(size_t)l * 64 + j];
    for (int i = 0; i < 128; i++) acc += s_g[w][i] * Wout[i * 64 + j];
    float m = acc;
    for (int o = 32; o >= 1; o >>= 1) m += __shfl_xor(m, o);
    m *= (1.f / 64.f);
    float dv = acc - m;
    float v = dv * dv;
    for (int o = 32; o >= 1; o >>= 1) v += __shfl_xor(v, o);
    v *= (1.f / 64.f);
    float out = dv * rsqrtf(v + 1e-5f) * lng[j] + lnb[j];
    int l2;
    if (permMode == 0) l2 = (l % 64) * 101 + (l / 64);   // (s,c)->(c,s)
    else               l2 = (l % 101) * 64 + (l / 101);  // (c,s)->(s,c)
    xnext[(size_t)l2 * 64 + j] = out;
    if (!doXz) return;
    // ---- next-layer xz for these 4 (permuted) rows: xz[l2] = out @ W_in
    s_out[w][j] = out;
    if (j == 0) s_l2[w] = l2;
    __syncthreads();
    float xa[4];
    #pragma unroll
    for (int r = 0; r < 4; r++) xa[r] = 0.f;
    for (int i = 0; i < 64; i++) {
        float wv = Win[i * 256 + tid];
        #pragma unroll
        for (int r = 0; r < 4; r++) xa[r] = fmaf(s_out[r][i], wv, xa[r]);
    }
    #pragma unroll
    for (int r = 0; r < 4; r++) xznext[(size_t)s_l2[r] * 256 + tid] = xa[r];
}

// ---------------- epilogue ----------------
__global__ void k_epilogue(const float* __restrict__ x, const float* __restrict__ Wfc,
                           const float* __restrict__ bfc, const float* __restrict__ ytrue,
                           const int* __restrict__ halfwin, const int* __restrict__ rows,
                           float* __restrict__ out) {
    int k = threadIdx.x;  // 64
    int hw = halfwin[0];
    int c = rows[k];
    const float* xr = x + ((size_t)hw * 64 + c) * 64;
    float acc = bfc[0];
    for (int i = 0; i < 64; i++) acc += xr[i] * Wfc[i];
    float s = 1.f / (1.f + expf(-acc));
    float r = 1.f - fabsf(ytrue[k] - s);
    out[k] = r;
}

extern "C" void kernel_launch(void* const* d_in, const int* in_sizes, int n_in,
                              void* d_out, int out_size, void* d_ws, size_t ws_size,
                              hipStream_t stream) {
    const float* DNA   = (const float*)d_in[0];
    const float* CpG   = (const float*)d_in[1];
    const float* cel   = (const float*)d_in[2];
    const float* pos   = (const float*)d_in[3];
    const float* ytrue = (const float*)d_in[4];
    const float* Wfcc  = (const float*)d_in[5];
    const float* bfcc  = (const float*)d_in[6];
    const float* Win   = (const float*)d_in[7];
    const float* convw = (const float*)d_in[8];
    const float* convb = (const float*)d_in[9];
    const float* Wxp   = (const float*)d_in[10];
    const float* Wdt   = (const float*)d_in[11];
    const float* bdt   = (const float*)d_in[12];
    const float* Alog  = (const float*)d_in[13];
    const float* Dres  = (const float*)d_in[14];
    const float* Wout  = (const float*)d_in[15];
    const float* lng   = (const float*)d_in[16];
    const float* lnb   = (const float*)d_in[17];
    const float* Wfc   = (const float*)d_in[18];
    const float* bfc   = (const float*)d_in[19];
    const int* halfwin = (const int*)d_in[20];
    const int* rows    = (const int*)d_in[21];

    float* ws = (float*)d_ws;
    size_t off = 0;
    float* x0  = ws + off; off += (size_t)L_SEQ * 64;
    float* x1  = ws + off; off += (size_t)L_SEQ * 64;
    float* xzA = ws + off; off += (size_t)L_SEQ * 256;
    float* xzB = ws + off; off += (size_t)L_SEQ * 256;
    float* xcb = ws + off; off += (size_t)2 * L_SEQ * 128;
    float* dtb = ws + off; off += (size_t)2 * L_SEQ * 128;
    float* BCb = ws + off; off += (size_t)2 * L_SEQ * 32;
    float* yb  = ws + off; off += (size_t)2 * L_SEQ * 128;
    float* cAb = ws + off; off += (size_t)CSZ;
    float* cBb = ws + off; off += (size_t)CSZ;
    float* Fb  = ws + off; off += (size_t)CSZ;
    float* cAm = ws + off; off += (size_t)CSZ;
    float* cBm = ws + off; off += (size_t)CSZ;

    float* xcur = x0;
    float* xnxt = x1;
    float* xzc  = xzA;
    float* xzn  = xzB;
    k_front0<<<L_SEQ / 8, 256, 0, stream>>>(DNA, CpG, cel, pos, Wfcc, bfcc, Win, x0, xzc);
    for (int sb = 0; sb < 8; sb++) {
        k_convdt<<<dim3(L_SEQ / 16, 2), 256, 0, stream>>>(xzc, convw, convb, Wxp, Wdt, bdt,
                                                          xcb, dtb, BCb);
        k_scanA<<<dim3(4, NCH, 2), 512, 0, stream>>>(dtb, xcb, BCb, Alog, cAb, cBb, cAm, cBm);
        k_fold<<<16, 256, 0, stream>>>(cAb, cBb, Fb);
        k_scanB<<<dim3(4, NCH, 2), 512, 0, stream>>>(dtb, xcb, BCb, Alog, Dres, Fb, cAm, cBm, yb);
        k_outln<<<L_SEQ / 4, 256, 0, stream>>>(xcur, yb, xzc, Wout, Win, lng, lnb, xnxt, xzn,
                                               (sb % 2 == 0) ? 0 : 1, (sb < 7) ? 1 : 0);
        float* tmp = xcur; xcur = xnxt; xnxt = tmp;
        float* tz = xzc; xzc = xzn; xzn = tz;
    }

    k_epilogue<<<1, 64, 0, stream>>>(xcur, Wfc, bfc, ytrue, halfwin, rows, (float*)d_out);
}